// Round 6
// baseline (335.811 us; speedup 1.0000x reference)
//
#include <hip/hip_runtime.h>

// ============================================================================
// ActorModel fused inference, MI355X (gfx950)
//
// Math restructuring (exact w.r.t. the reference up to fp rounding):
//   h0 == 0, c0 == 0 (fixed zero inputs)  =>  Whh term and f-gate vanish.
//   gates = [wave|wait|neigh][B,72] @ Wf.T + bias_f     (branch Linears folded)
//   i,o rows pre-scaled by -log2e ; g rows by +2*log2e  (activations -> exp2)
//   c = sig(i)*tanh(g) = (Eg-1) / ((1+Ei)(1+Eg)),  Ei=2^i', Eg=2^g'
//   h = sig(o)*tanh(c) = (Ec-1) / ((1+Eo)(1+Ec)),  Ec=2^(2c*log2e)
//   out = softmax(h @ Wout.T + bout)
//
// Structure: gates^T via mfma(W_frag, X_frag) so activated h lands exactly in
// the B-fragment layout of mfma_f32_16x16x16_f16; the 548->8 head is MFMA
// accumulation (logits^T), not scalar FMAs. Inputs staged f32->f16 in-kernel
// via LDS; 2 dispatches total.
//
// R6: desk model says the trans pipe (4 exp2 + 2 rcp per h, quarter-rate)
// is the binding resource (~14us). Changes: (1) __has_builtin guards for
// exp2/rcp builtins (compile-risk hedge); (2) two-pass activation (all 24
// exp2 batched, then rcp chains) for trans-pipe ILP at 2 waves/SIMD;
// (3) (Eg-1)*2log2e folded into one fma.
//
// Precision: fp16 operands (values are small: |gates|<~6, weights <0.2) —
// 11-bit mantissa cuts GEMM rounding 8x vs bf16; f16 MFMA rate == bf16.
// ============================================================================

#define LOG2E 1.4426950408889634f

typedef _Float16 half8v __attribute__((ext_vector_type(8)));
typedef _Float16 half4v __attribute__((ext_vector_type(4)));
typedef float float4v __attribute__((ext_vector_type(4)));

#if defined(__has_builtin)
#  if __has_builtin(__builtin_amdgcn_mfma_f32_16x16x16f16)
#    define MFMA16(a, b, c) __builtin_amdgcn_mfma_f32_16x16x16f16(a, b, c, 0, 0, 0)
#  elif __has_builtin(__builtin_amdgcn_mfma_f32_16x16x16_f16)
#    define MFMA16(a, b, c) __builtin_amdgcn_mfma_f32_16x16x16_f16(a, b, c, 0, 0, 0)
#  else
#    define MFMA16(a, b, c) __builtin_amdgcn_mfma_f32_16x16x16f16(a, b, c, 0, 0, 0)
#  endif
#  if __has_builtin(__builtin_amdgcn_exp2f)
#    define EXP2(x) __builtin_amdgcn_exp2f(x)
#  else
#    define EXP2(x) __builtin_exp2f(x)   // fexp2 f32 is Legal on amdgcn -> v_exp_f32
#  endif
#  if __has_builtin(__builtin_amdgcn_rcpf)
#    define RCP(x) __builtin_amdgcn_rcpf(x)
#  else
#    define RCP(x) (1.0f / (x))
#  endif
#else
#  define MFMA16(a, b, c) __builtin_amdgcn_mfma_f32_16x16x16f16(a, b, c, 0, 0, 0)
#  define EXP2(x) __builtin_exp2f(x)
#  define RCP(x) (1.0f / (x))
#endif

__device__ __forceinline__ unsigned short f2h(float x) {
  return __builtin_bit_cast(unsigned short, (_Float16)x);
}

// ---------------------------------------------------------------------------
// Wf layout: [35 ntile][10240 B tile]; tile = [3 gate][16 unit][104 f16 (k,
// 96 used + 8 pad)] + 256 B tail pad  => 640 uint4 / tile.
// Blocks 0..629: Wf fold.  Blocks 630..636: biasF fold.
// ---------------------------------------------------------------------------
__global__ void prep_wb(const float* __restrict__ Wih, const float* __restrict__ W1,
                        const float* __restrict__ W2, const float* __restrict__ W3,
                        const float* __restrict__ b1, const float* __restrict__ b2,
                        const float* __restrict__ b3, const float* __restrict__ bih,
                        const float* __restrict__ bhh,
                        unsigned short* __restrict__ Wf, float* __restrict__ biasF) {
  if (blockIdx.x < 630) {
    int idx = blockIdx.x * 256 + threadIdx.x;        // 3*560*96 = 161280 exact
    int k = idx % 96;
    int u = (idx / 96) % 560;
    int t = idx / (96 * 560);                        // 0:i 1:g 2:o
    float val = 0.f;
    if (u < 548 && k < 72) {
      int row = u + (t == 0 ? 0 : (t == 1 ? 1096 : 1644));
      const float* wr = Wih + (size_t)row * 224;
      float s = 0.f;
      if (k < 12) {
        #pragma unroll 16
        for (int m = 0; m < 128; ++m) s += wr[m] * W1[m * 12 + k];
      } else if (k < 24) {
        int kk = k - 12;
        #pragma unroll 16
        for (int m = 0; m < 32; ++m) s += wr[128 + m] * W2[m * 12 + kk];
      } else {
        int kk = k - 24;
        #pragma unroll 16
        for (int m = 0; m < 64; ++m) s += wr[160 + m] * W3[m * 48 + kk];
      }
      val = s * (t == 1 ? 2.f * LOG2E : -LOG2E);
    }
    size_t off = (size_t)(u >> 4) * 5120 + (size_t)t * 1664 + (size_t)(u & 15) * 104 + k;
    Wf[off] = f2h(val);
  } else {
    int idx = (blockIdx.x - 630) * 256 + threadIdx.x;
    if (idx >= 1680) return;
    int u = idx % 560, t = idx / 560;
    float val = 0.f;
    if (u < 548) {
      int row = u + (t == 0 ? 0 : (t == 1 ? 1096 : 1644));
      const float* wr = Wih + (size_t)row * 224;
      float s = bih[row] + bhh[row];
      #pragma unroll 16
      for (int m = 0; m < 128; ++m) s += wr[m] * b1[m];
      #pragma unroll 16
      for (int m = 0; m < 32; ++m) s += wr[128 + m] * b2[m];
      #pragma unroll 16
      for (int m = 0; m < 64; ++m) s += wr[160 + m] * b3[m];
      val = s * (t == 1 ? 2.f * LOG2E : -LOG2E);
    }
    biasF[t * 560 + u] = val;                        // pad units exact 0 -> h=0
  }
}

// ---------------------------------------------------------------------------
__global__ __launch_bounds__(256) void fused_main(
    const float* __restrict__ wv, const float* __restrict__ wt,
    const float* __restrict__ ng, const uint4* __restrict__ Wf,
    const float* __restrict__ biasF, const float* __restrict__ Wout,
    const float* __restrict__ bout, float* __restrict__ out) {
  __shared__ uint4 sbuf[2][640];                                   // 20480 B dbuf
  __shared__ __attribute__((aligned(16))) uint2 sA2[35 * 64];      // 17920 B Wout frags
  __shared__ __attribute__((aligned(16))) float sBias[1680];       //  6720 B
  __shared__ __attribute__((aligned(16))) _Float16 sX[128 * 80 + 16];  // 20512 B (+zero tail)

  const int tid = threadIdx.x;
  const int wvi = tid >> 6, lane = tid & 63;
  const int l15 = lane & 15, grp = lane >> 4;
  const int bb0 = blockIdx.x * 128;                  // block's first batch

  // ---- stage this block's inputs f32 -> f16 LDS: sX[blk_batch][k<80] ----
  for (int i = tid; i < 1536; i += 256)              // wave: k 0..11
    sX[(i / 12) * 80 + (i % 12)] = (_Float16)wv[(size_t)bb0 * 12 + i];
  for (int i = tid; i < 1536; i += 256)              // wait: k 12..23
    sX[(i / 12) * 80 + 12 + (i % 12)] = (_Float16)wt[(size_t)bb0 * 12 + i];
  for (int i = tid; i < 6144; i += 256)              // neigh: k 24..71
    sX[(i / 48) * 80 + 24 + (i % 48)] = (_Float16)ng[(size_t)bb0 * 48 + i];
  for (int i = tid; i < 1024; i += 256)              // pad: k 72..79
    sX[(i >> 3) * 80 + 72 + (i & 7)] = (_Float16)0.f;
  if (tid < 16) sX[128 * 80 + tid] = (_Float16)0.f;  // zeroed tail (OOB fix)

  // Wout in 16x16x16 A-frag order: lane l, slot j -> Wout[p=l&15][t*16+(l>>4)*4+j]
  for (int idx = tid; idx < 35 * 64; idx += 256) {
    const int t = idx >> 6, l = idx & 63;
    const int p = l & 15, g = l >> 4;
    half4v w4;
    #pragma unroll
    for (int j = 0; j < 4; ++j) {
      const int u = t * 16 + g * 4 + j;
      const float v = (p < 8 && u < 548) ? Wout[p * 548 + u] : 0.f;
      w4[j] = (_Float16)v;
    }
    sA2[idx] = __builtin_bit_cast(uint2, w4);
  }
  for (int i = tid; i < 1680; i += 256) sBias[i] = biasF[i];

  // stage ntile 0
  sbuf[0][tid] = Wf[tid];
  sbuf[0][256 + tid] = Wf[256 + tid];
  if (tid < 128) sbuf[0][512 + tid] = Wf[512 + tid];
  __syncthreads();

  // X B-fragments from sX: lane=(k_grp<<4)|batch, k = kc*32 + grp*8 + j.
  // kc=2,grp>=2 intentionally overlaps the next row: Wf k>=72 is exact zero,
  // so aliased finite values contribute 0; last row is backed by the zero tail.
  half8v xfrag[2][3];
  #pragma unroll
  for (int mt = 0; mt < 2; ++mt)
    #pragma unroll
    for (int kc = 0; kc < 3; ++kc) {
      const int bl = wvi * 32 + mt * 16 + l15;
      xfrag[mt][kc] = *(const half8v*)&sX[bl * 80 + kc * 32 + grp * 8];
    }

  float4v acc2[2] = {{0.f, 0.f, 0.f, 0.f}, {0.f, 0.f, 0.f, 0.f}};  // logits^T

  for (int t = 0; t < 35; ++t) {
    const int cur = t & 1;
    const bool pf = (t + 1 < 35);
    uint4 s0, s1, s2;                                // issue-early (T14)
    if (pf) {
      const size_t g = (size_t)(t + 1) * 640;
      s0 = Wf[g + tid];
      s1 = Wf[g + 256 + tid];
      if (tid < 128) s2 = Wf[g + 512 + tid];
    }

    // bias for units t*16+grp*4 .. +3, per gate
    float4v bi4[3];
    #pragma unroll
    for (int g3 = 0; g3 < 3; ++g3)
      bi4[g3] = *(const float4v*)&sBias[g3 * 560 + t * 16 + grp * 4];

    const char* base = (const char*)sbuf[cur];
    half8v bw[3][3];                                 // W A-fragments
    #pragma unroll
    for (int g3 = 0; g3 < 3; ++g3)
      #pragma unroll
      for (int kc = 0; kc < 3; ++kc)
        bw[g3][kc] = *(const half8v*)(base + g3 * 3328 + l15 * 208 + kc * 64 + grp * 16);

    float4v acc[3][2];
    #pragma unroll
    for (int g3 = 0; g3 < 3; ++g3)
      #pragma unroll
      for (int mt = 0; mt < 2; ++mt) acc[g3][mt] = bi4[g3];

    // gates^T: D[unit = grp*4+r][batch = l15]
    #pragma unroll
    for (int kc = 0; kc < 3; ++kc)
      #pragma unroll
      for (int g3 = 0; g3 < 3; ++g3)
        #pragma unroll
        for (int mt = 0; mt < 2; ++mt)
          acc[g3][mt] = __builtin_amdgcn_mfma_f32_16x16x32_f16(
              bw[g3][kc], xfrag[mt][kc], acc[g3][mt], 0, 0, 0);

    const half4v a2 = __builtin_bit_cast(half4v, sA2[t * 64 + lane]);

    // ---- two-pass activation: batch independent trans ops for pipe ILP ----
    float Ei[2][4], Eg[2][4], Eo[2][4];              // pass 1: 24 exp2
    #pragma unroll
    for (int mt = 0; mt < 2; ++mt)
      #pragma unroll
      for (int r = 0; r < 4; ++r) {
        Ei[mt][r] = EXP2(acc[0][mt][r]);             // e^{-i}
        Eg[mt][r] = EXP2(acc[1][mt][r]);             // e^{2g}
        Eo[mt][r] = EXP2(acc[2][mt][r]);             // e^{-o}
      }
    float c2[2][4];                                  // pass 2: 8 rcp -> c*2log2e
    #pragma unroll
    for (int mt = 0; mt < 2; ++mt)
      #pragma unroll
      for (int r = 0; r < 4; ++r) {
        const float den = (1.f + Ei[mt][r]) * (1.f + Eg[mt][r]);
        const float num = __builtin_fmaf(Eg[mt][r], 2.f * LOG2E, -2.f * LOG2E);
        c2[mt][r] = num * RCP(den);                  // = 2*log2e * c
      }
    float Ec[2][4];                                  // pass 3: 8 exp2
    #pragma unroll
    for (int mt = 0; mt < 2; ++mt)
      #pragma unroll
      for (int r = 0; r < 4; ++r) Ec[mt][r] = EXP2(c2[mt][r]);

    #pragma unroll
    for (int mt = 0; mt < 2; ++mt) {                 // pass 4: 8 rcp -> h, cvt
      half4v hh;                                     // h in B-frag layout
      #pragma unroll
      for (int r = 0; r < 4; ++r) {
        const float den = (1.f + Eo[mt][r]) * (1.f + Ec[mt][r]);
        const float h = (Ec[mt][r] - 1.f) * RCP(den);
        hh[r] = (_Float16)h;
      }
      acc2[mt] = MFMA16(a2, hh, acc2[mt]);           // logits^T[p][b] +=
    }

    if (pf) {                                        // write-late
      sbuf[cur ^ 1][tid] = s0;
      sbuf[cur ^ 1][256 + tid] = s1;
      if (tid < 128) sbuf[cur ^ 1][512 + tid] = s2;
    }
    __syncthreads();
  }

  // Epilogue: lane (grp<2, b=l15) holds logits[p = grp*4+r][batch0+mt*16+b]
  const int batch0 = bb0 + wvi * 32;
  if (grp < 2) {
    const float4v bo4 = *(const float4v*)(bout + grp * 4);
    #pragma unroll
    for (int mt = 0; mt < 2; ++mt) {
      float l[4];
      #pragma unroll
      for (int r = 0; r < 4; ++r) l[r] = acc2[mt][r] + bo4[r];
      float mymax = fmaxf(fmaxf(l[0], l[1]), fmaxf(l[2], l[3]));
      const float mx = fmaxf(mymax, __shfl_xor(mymax, 16, 64));
      float e[4], s = 0.f;
      #pragma unroll
      for (int r = 0; r < 4; ++r) {
        e[r] = EXP2((l[r] - mx) * LOG2E);
        s += e[r];
      }
      s += __shfl_xor(s, 16, 64);
      const float rs = RCP(s);
      float4v res;
      #pragma unroll
      for (int r = 0; r < 4; ++r) res[r] = e[r] * rs;
      const int batch = batch0 + mt * 16 + l15;
      *(float4v*)(out + (size_t)batch * 8 + grp * 4) = res;
    }
  }
}

// ---------------------------------------------------------------------------
extern "C" void kernel_launch(void* const* d_in, const int* in_sizes, int n_in,
                              void* d_out, int out_size, void* d_ws, size_t ws_size,
                              hipStream_t stream) {
  const float* wave  = (const float*)d_in[0];
  const float* wait_ = (const float*)d_in[1];
  const float* neigh = (const float*)d_in[2];
  const float* W1    = (const float*)d_in[3];
  const float* b1    = (const float*)d_in[4];
  const float* W2    = (const float*)d_in[5];
  const float* b2    = (const float*)d_in[6];
  const float* W3    = (const float*)d_in[7];
  const float* b3    = (const float*)d_in[8];
  const float* Wih   = (const float*)d_in[9];
  // d_in[10] = Whh  (unused: h0 == 0)
  const float* bih   = (const float*)d_in[11];
  const float* bhh   = (const float*)d_in[12];
  const float* Wout  = (const float*)d_in[13];
  const float* bout  = (const float*)d_in[14];
  // d_in[15] = h0, d_in[16] = c0 (zero, unused)
  float* out = (float*)d_out;

  char* ws = (char*)d_ws;
  unsigned short* Wf = (unsigned short*)(ws);        //      0 .. 358400
  float* biasF = (float*)(ws + 358400);              // 358400 .. 365120 (total 365 KB)

  hipLaunchKernelGGL(prep_wb, dim3(637), dim3(256), 0, stream,
                     Wih, W1, W2, W3, b1, b2, b3, bih, bhh, Wf, biasF);
  hipLaunchKernelGGL(fused_main, dim3(512), dim3(256), 0, stream,
                     wave, wait_, neigh, (const uint4*)Wf, biasF, Wout, bout, out);
}

// Round 7
// 327.279 us; speedup vs baseline: 1.0261x; 1.0261x over previous
//
#include <hip/hip_runtime.h>

// ============================================================================
// ActorModel fused inference, MI355X (gfx950)
//
// Math restructuring (exact w.r.t. the reference up to fp rounding):
//   h0 == 0, c0 == 0 (fixed zero inputs)  =>  Whh term and f-gate vanish.
//   gates = [wave|wait|neigh][B,72] @ Wf.T + bias_f     (branch Linears folded)
//   i,o rows pre-scaled by -log2e ; g rows by +2*log2e  (activations -> exp2)
//   c = sig(i)*tanh(g) = (Eg-1) / ((1+Ei)(1+Eg)),  Ei=2^i', Eg=2^g'
//   h = sig(o)*tanh(c) = (Ec-1) / ((1+Eo)(1+Ec)),  Ec=2^(2c*log2e)
//   out = softmax(h @ Wout.T + bout)
//
// R7 (first round with real counters; dur 335.8us, absmax 9.8e-4 PASSED):
// top-5 dispatches are all harness 0xAA poison fills of the 574MB workspace
// (85us each); our kernels are each <82us. Theory: fused_main was lockstep-
// bound (2 blocks/CU, barrier-synced waves serialize MFMA phase and VALU/
// trans phase, m190 mechanism). Fix (m114 mechanism): 1024 blocks x 64
// batches, sA2 moved from LDS to L2-resident per-iter load -> LDS 37.5KB ->
// 4 blocks/CU, 16 waves/CU; unsynchronized blocks on each SIMD overlap one
// block's MFMA with another's activation VALU.
//
// Precision: fp16 operands; measured absmax 9.8e-4. f16 MFMA rate == bf16.
// ============================================================================

#define LOG2E 1.4426950408889634f

typedef _Float16 half8v __attribute__((ext_vector_type(8)));
typedef _Float16 half4v __attribute__((ext_vector_type(4)));
typedef float float4v __attribute__((ext_vector_type(4)));

#if defined(__has_builtin)
#  if __has_builtin(__builtin_amdgcn_mfma_f32_16x16x16f16)
#    define MFMA16(a, b, c) __builtin_amdgcn_mfma_f32_16x16x16f16(a, b, c, 0, 0, 0)
#  elif __has_builtin(__builtin_amdgcn_mfma_f32_16x16x16_f16)
#    define MFMA16(a, b, c) __builtin_amdgcn_mfma_f32_16x16x16_f16(a, b, c, 0, 0, 0)
#  else
#    define MFMA16(a, b, c) __builtin_amdgcn_mfma_f32_16x16x16f16(a, b, c, 0, 0, 0)
#  endif
#  if __has_builtin(__builtin_amdgcn_exp2f)
#    define EXP2(x) __builtin_amdgcn_exp2f(x)
#  else
#    define EXP2(x) __builtin_exp2f(x)
#  endif
#  if __has_builtin(__builtin_amdgcn_rcpf)
#    define RCP(x) __builtin_amdgcn_rcpf(x)
#  else
#    define RCP(x) (1.0f / (x))
#  endif
#else
#  define MFMA16(a, b, c) __builtin_amdgcn_mfma_f32_16x16x16f16(a, b, c, 0, 0, 0)
#  define EXP2(x) __builtin_exp2f(x)
#  define RCP(x) (1.0f / (x))
#endif

__device__ __forceinline__ unsigned short f2h(float x) {
  return __builtin_bit_cast(unsigned short, (_Float16)x);
}

// ---------------------------------------------------------------------------
// Wf layout: [35 ntile][10240 B tile]; tile = [3 gate][16 unit][104 f16 (k,
// 96 used + 8 pad)] + 256 B tail pad  => 640 uint4 / tile.
// Blocks 0..629: Wf fold. Blocks 630..636: biasF. Block 637: WoutF frags.
// ---------------------------------------------------------------------------
__global__ void prep_wb(const float* __restrict__ Wih, const float* __restrict__ W1,
                        const float* __restrict__ W2, const float* __restrict__ W3,
                        const float* __restrict__ b1, const float* __restrict__ b2,
                        const float* __restrict__ b3, const float* __restrict__ bih,
                        const float* __restrict__ bhh, const float* __restrict__ Wout,
                        unsigned short* __restrict__ Wf, float* __restrict__ biasF,
                        uint2* __restrict__ WoutF) {
  if (blockIdx.x < 630) {
    int idx = blockIdx.x * 256 + threadIdx.x;        // 3*560*96 = 161280 exact
    int k = idx % 96;
    int u = (idx / 96) % 560;
    int t = idx / (96 * 560);                        // 0:i 1:g 2:o
    float val = 0.f;
    if (u < 548 && k < 72) {
      int row = u + (t == 0 ? 0 : (t == 1 ? 1096 : 1644));
      const float* wr = Wih + (size_t)row * 224;
      float s = 0.f;
      if (k < 12) {
        #pragma unroll 16
        for (int m = 0; m < 128; ++m) s += wr[m] * W1[m * 12 + k];
      } else if (k < 24) {
        int kk = k - 12;
        #pragma unroll 16
        for (int m = 0; m < 32; ++m) s += wr[128 + m] * W2[m * 12 + kk];
      } else {
        int kk = k - 24;
        #pragma unroll 16
        for (int m = 0; m < 64; ++m) s += wr[160 + m] * W3[m * 48 + kk];
      }
      val = s * (t == 1 ? 2.f * LOG2E : -LOG2E);
    }
    size_t off = (size_t)(u >> 4) * 5120 + (size_t)t * 1664 + (size_t)(u & 15) * 104 + k;
    Wf[off] = f2h(val);
  } else if (blockIdx.x < 637) {
    int idx = (blockIdx.x - 630) * 256 + threadIdx.x;
    if (idx >= 1680) return;
    int u = idx % 560, t = idx / 560;
    float val = 0.f;
    if (u < 548) {
      int row = u + (t == 0 ? 0 : (t == 1 ? 1096 : 1644));
      const float* wr = Wih + (size_t)row * 224;
      float s = bih[row] + bhh[row];
      #pragma unroll 16
      for (int m = 0; m < 128; ++m) s += wr[m] * b1[m];
      #pragma unroll 16
      for (int m = 0; m < 32; ++m) s += wr[128 + m] * b2[m];
      #pragma unroll 16
      for (int m = 0; m < 64; ++m) s += wr[160 + m] * b3[m];
      val = s * (t == 1 ? 2.f * LOG2E : -LOG2E);
    }
    biasF[t * 560 + u] = val;                        // pad units exact 0 -> h=0
  } else {
    // Wout in 16x16x16 A-frag order: entry (t,l): row p=l&15, k=t*16+(l>>4)*4+j
    for (int idx = threadIdx.x; idx < 35 * 64; idx += 256) {
      const int t = idx >> 6, l = idx & 63;
      const int p = l & 15, g = l >> 4;
      half4v w4;
      #pragma unroll
      for (int j = 0; j < 4; ++j) {
        const int u = t * 16 + g * 4 + j;
        const float v = (p < 8 && u < 548) ? Wout[p * 548 + u] : 0.f;
        w4[j] = (_Float16)v;
      }
      WoutF[idx] = __builtin_bit_cast(uint2, w4);
    }
  }
}

// ---------------------------------------------------------------------------
__global__ __launch_bounds__(256, 3) void fused_main(
    const float* __restrict__ wv, const float* __restrict__ wt,
    const float* __restrict__ ng, const uint4* __restrict__ Wf,
    const float* __restrict__ biasF, const uint2* __restrict__ WoutF,
    const float* __restrict__ bout, float* __restrict__ out) {
  __shared__ uint4 sbuf[2][640];                                   // 20480 B dbuf
  __shared__ __attribute__((aligned(16))) float sBias[1680];       //  6720 B
  __shared__ __attribute__((aligned(16))) _Float16 sX[64 * 80 + 16];  // 10272 B (+zero tail)
  // total 37472 B -> 4 blocks/CU (16 waves/CU): cross-block MFMA/VALU overlap

  const int tid = threadIdx.x;
  const int wvi = tid >> 6, lane = tid & 63;
  const int l15 = lane & 15, grp = lane >> 4;
  const int bb0 = blockIdx.x * 64;                   // block's first batch

  // ---- stage this block's inputs f32 -> f16 LDS: sX[blk_batch][k<80] ----
  for (int i = tid; i < 768; i += 256)               // wave: k 0..11
    sX[(i / 12) * 80 + (i % 12)] = (_Float16)wv[(size_t)bb0 * 12 + i];
  for (int i = tid; i < 768; i += 256)               // wait: k 12..23
    sX[(i / 12) * 80 + 12 + (i % 12)] = (_Float16)wt[(size_t)bb0 * 12 + i];
  for (int i = tid; i < 3072; i += 256)              // neigh: k 24..71
    sX[(i / 48) * 80 + 24 + (i % 48)] = (_Float16)ng[(size_t)bb0 * 48 + i];
  for (int i = tid; i < 512; i += 256)               // pad: k 72..79
    sX[(i >> 3) * 80 + 72 + (i & 7)] = (_Float16)0.f;
  if (tid < 16) sX[64 * 80 + tid] = (_Float16)0.f;   // zeroed tail (OOB guard)

  for (int i = tid; i < 1680; i += 256) sBias[i] = biasF[i];

  // stage ntile 0
  sbuf[0][tid] = Wf[tid];
  sbuf[0][256 + tid] = Wf[256 + tid];
  if (tid < 128) sbuf[0][512 + tid] = Wf[512 + tid];
  __syncthreads();

  // X B-fragments from sX: lane=(k_grp<<4)|batch, k = kc*32 + grp*8 + j.
  // kc=2,grp>=2 intentionally overlaps the next row (Wf k>=72 is exact zero,
  // 0*finite=0); last row is backed by the zero tail.
  half8v xfrag[3];
  const int bl = wvi * 16 + l15;
  #pragma unroll
  for (int kc = 0; kc < 3; ++kc)
    xfrag[kc] = *(const half8v*)&sX[bl * 80 + kc * 32 + grp * 8];

  float4v acc2 = {0.f, 0.f, 0.f, 0.f};               // logits^T

  for (int t = 0; t < 35; ++t) {
    const int cur = t & 1;
    const bool pf = (t + 1 < 35);
    const uint2 a2w = WoutF[t * 64 + lane];          // L2-resident, issue-early
    uint4 s0, s1, s2;                                // issue-early (T14)
    if (pf) {
      const size_t g = (size_t)(t + 1) * 640;
      s0 = Wf[g + tid];
      s1 = Wf[g + 256 + tid];
      if (tid < 128) s2 = Wf[g + 512 + tid];
    }

    // bias for units t*16+grp*4 .. +3, per gate
    float4v bi4[3];
    #pragma unroll
    for (int g3 = 0; g3 < 3; ++g3)
      bi4[g3] = *(const float4v*)&sBias[g3 * 560 + t * 16 + grp * 4];

    const char* base = (const char*)sbuf[cur];
    half8v bw[3][3];                                 // W A-fragments
    #pragma unroll
    for (int g3 = 0; g3 < 3; ++g3)
      #pragma unroll
      for (int kc = 0; kc < 3; ++kc)
        bw[g3][kc] = *(const half8v*)(base + g3 * 3328 + l15 * 208 + kc * 64 + grp * 16);

    float4v acc[3];
    #pragma unroll
    for (int g3 = 0; g3 < 3; ++g3) acc[g3] = bi4[g3];

    // gates^T: D[unit = grp*4+r][batch = l15]
    #pragma unroll
    for (int kc = 0; kc < 3; ++kc)
      #pragma unroll
      for (int g3 = 0; g3 < 3; ++g3)
        acc[g3] = __builtin_amdgcn_mfma_f32_16x16x32_f16(
            bw[g3][kc], xfrag[kc], acc[g3], 0, 0, 0);

    // ---- two-pass activation: batch independent trans ops for pipe ILP ----
    float Ei[4], Eg[4], Eo[4];                       // pass 1: 12 exp2
    #pragma unroll
    for (int r = 0; r < 4; ++r) {
      Ei[r] = EXP2(acc[0][r]);                       // e^{-i}
      Eg[r] = EXP2(acc[1][r]);                       // e^{2g}
      Eo[r] = EXP2(acc[2][r]);                       // e^{-o}
    }
    float c2[4];                                     // pass 2: 4 rcp
    #pragma unroll
    for (int r = 0; r < 4; ++r) {
      const float den = (1.f + Ei[r]) * (1.f + Eg[r]);
      const float num = __builtin_fmaf(Eg[r], 2.f * LOG2E, -2.f * LOG2E);
      c2[r] = num * RCP(den);                        // = 2*log2e * c
    }
    float Ec[4];                                     // pass 3: 4 exp2
    #pragma unroll
    for (int r = 0; r < 4; ++r) Ec[r] = EXP2(c2[r]);
    half4v hh;                                       // pass 4: 4 rcp -> h
    #pragma unroll
    for (int r = 0; r < 4; ++r) {
      const float den = (1.f + Eo[r]) * (1.f + Ec[r]);
      hh[r] = (_Float16)((Ec[r] - 1.f) * RCP(den));
    }

    const half4v a2 = __builtin_bit_cast(half4v, a2w);
    acc2 = MFMA16(a2, hh, acc2);                     // logits^T[p][b] +=

    if (pf) {                                        // write-late
      sbuf[cur ^ 1][tid] = s0;
      sbuf[cur ^ 1][256 + tid] = s1;
      if (tid < 128) sbuf[cur ^ 1][512 + tid] = s2;
    }
    __syncthreads();
  }

  // Epilogue: lane (grp<2, b=l15) holds logits[p = grp*4+r][bb0+wvi*16+b]
  if (grp < 2) {
    const float4v bo4 = *(const float4v*)(bout + grp * 4);
    float l[4];
    #pragma unroll
    for (int r = 0; r < 4; ++r) l[r] = acc2[r] + bo4[r];
    float mymax = fmaxf(fmaxf(l[0], l[1]), fmaxf(l[2], l[3]));
    const float mx = fmaxf(mymax, __shfl_xor(mymax, 16, 64));
    float e[4], s = 0.f;
    #pragma unroll
    for (int r = 0; r < 4; ++r) {
      e[r] = EXP2((l[r] - mx) * LOG2E);
      s += e[r];
    }
    s += __shfl_xor(s, 16, 64);
    const float rs = RCP(s);
    float4v res;
    #pragma unroll
    for (int r = 0; r < 4; ++r) res[r] = e[r] * rs;
    const int batch = bb0 + wvi * 16 + l15;
    *(float4v*)(out + (size_t)batch * 8 + grp * 4) = res;
  }
}

// ---------------------------------------------------------------------------
extern "C" void kernel_launch(void* const* d_in, const int* in_sizes, int n_in,
                              void* d_out, int out_size, void* d_ws, size_t ws_size,
                              hipStream_t stream) {
  const float* wave  = (const float*)d_in[0];
  const float* wait_ = (const float*)d_in[1];
  const float* neigh = (const float*)d_in[2];
  const float* W1    = (const float*)d_in[3];
  const float* b1    = (const float*)d_in[4];
  const float* W2    = (const float*)d_in[5];
  const float* b2    = (const float*)d_in[6];
  const float* W3    = (const float*)d_in[7];
  const float* b3    = (const float*)d_in[8];
  const float* Wih   = (const float*)d_in[9];
  // d_in[10] = Whh  (unused: h0 == 0)
  const float* bih   = (const float*)d_in[11];
  const float* bhh   = (const float*)d_in[12];
  const float* Wout  = (const float*)d_in[13];
  const float* bout  = (const float*)d_in[14];
  // d_in[15] = h0, d_in[16] = c0 (zero, unused)
  float* out = (float*)d_out;

  char* ws = (char*)d_ws;
  unsigned short* Wf = (unsigned short*)(ws);        //      0 .. 358400
  float* biasF = (float*)(ws + 358400);              // 358400 .. 365120
  uint2* WoutF = (uint2*)(ws + 365120);              // 365120 .. 383040 (383 KB total)

  hipLaunchKernelGGL(prep_wb, dim3(638), dim3(256), 0, stream,
                     Wih, W1, W2, W3, b1, b2, b3, bih, bhh, Wout, Wf, biasF, WoutF);
  hipLaunchKernelGGL(fused_main, dim3(1024), dim3(256), 0, stream,
                     wave, wait_, neigh, (const uint4*)Wf, biasF, WoutF, bout, out);
}